// Round 1
// baseline (246.499 us; speedup 1.0000x reference)
//
#include <hip/hip_runtime.h>
#include <hip/hip_bf16.h>

typedef __attribute__((ext_vector_type(8))) short short8;
typedef __attribute__((ext_vector_type(16))) float floatx16;

#define Bn 32
#define Ln 512
#define Cn 300
#define Hn 512
#define Nn (Bn*Ln)          // 16384
#define XBP 518             // 512 + 3 halo each side
#define XBC 320             // channels padded to 10*32
#define HK 1216             // 1200 padded to 38*32

// workspace layout in bf16 elements
#define XB_OFF 0
#define XB_ELEMS (Bn*XBP*XBC)           // 5,304,320
#define WB_OFF (XB_OFF + XB_ELEMS)
#define WB_ELEMS 1597440                 // 384*320*(1+2+3+7)
#define WC_OFF (WB_OFF + WB_ELEMS)
#define WC_ELEMS (Hn*HK)
#define HB_OFF (WC_OFF + WC_ELEMS)
#define HB_ELEMS (Nn*HK)

// ---------------- prep kernels ----------------

__global__ void prep_x(const float* __restrict__ x, __hip_bfloat16* __restrict__ xb) {
    int idx = blockIdx.x * 256 + threadIdx.x;
    if (idx >= Bn * XBP * XBC) return;
    int c = idx % XBC;
    int t = idx / XBC;
    int p = t % XBP;
    int b = t / XBP;
    int l = p - 3;
    l = l < 0 ? 0 : (l > Ln - 1 ? Ln - 1 : l);   // replication pad
    float v = (c < Cn) ? x[(b * Ln + l) * Cn + c] : 0.f;
    xb[idx] = __float2bfloat16(v);
}

// layout per conv: base + m*(320*taps) + chunk*(32*taps) + tap*32 + ci ; m in [0,384)
__global__ void prep_w(const float* __restrict__ w1, const float* __restrict__ w2,
                       const float* __restrict__ w3, const float* __restrict__ w7,
                       __hip_bfloat16* __restrict__ Wb) {
    int idx = blockIdx.x * 256 + threadIdx.x;
    if (idx >= WB_ELEMS) return;
    int r = idx, taps; const float* w;
    if (r < 122880)       { taps = 1; w = w1; }
    else if (r < 368640)  { taps = 2; w = w2; r -= 122880; }
    else if (r < 737280)  { taps = 3; w = w3; r -= 368640; }
    else                  { taps = 7; w = w7; r -= 737280; }
    int per_m = 320 * taps;
    int m  = r / per_m;
    int r2 = r % per_m;
    int chunk = r2 / (32 * taps);
    int r3    = r2 % (32 * taps);
    int tap = r3 / 32;
    int ci  = r3 % 32;
    int c = chunk * 32 + ci;
    float v = (m < Cn && c < Cn) ? w[(m * Cn + c) * taps + tap] : 0.f;
    Wb[idx] = __float2bfloat16(v);
}

// combined linear weight: cols 0-599 = slp cols 0-599, 600-899 = col k + col k+300 (x3+x5),
// 900-1199 = col k+300 (x7), 1200-1215 = 0
__global__ void prep_wc(const float* __restrict__ slp_w, __hip_bfloat16* __restrict__ Wc) {
    int idx = blockIdx.x * 256 + threadIdx.x;
    if (idx >= Hn * HK) return;
    int k = idx % HK;
    int h = idx / HK;
    const float* row = slp_w + h * 1500;
    float v;
    if (k < 600)       v = row[k];
    else if (k < 900)  v = row[k] + row[k + 300];
    else if (k < 1200) v = row[k + 300];
    else               v = 0.f;
    Wc[idx] = __float2bfloat16(v);
}

// ---------------- conv GEMM ----------------
// grid (128 n-tiles, 12 m-tiles = 4 convs x 3 tiles of 128), block 256
// block tile: 128 positions x 128 out-channels; wave tile 64x64 (2x2 of 32x32x16 bf16 MFMA)
__global__ __launch_bounds__(256) void conv_kernel(
        const __hip_bfloat16* __restrict__ xbg, const __hip_bfloat16* __restrict__ Wbg,
        const float* __restrict__ bias1, const float* __restrict__ bias2,
        const float* __restrict__ bias3, const float* __restrict__ bias7,
        __hip_bfloat16* __restrict__ hbuf) {
    __shared__ __align__(16) short xs[134 * 40];   // 134 position rows x 32 ch (pad to 40)
    __shared__ __align__(16) short wl[128 * 40];   // 128 m rows x 32 k (pad to 40)

    const int tid  = threadIdx.x;
    const int lane = tid & 63;
    const int wave = tid >> 6;
    const int wn = wave & 1, wm = wave >> 1;
    const int lr = lane & 31;
    const int lk = (lane >> 5) * 8;

    const int nt   = blockIdx.x;
    const int my   = blockIdx.y;
    const int conv = my / 3;
    const int m0   = (my % 3) * 128;

    const int taps  = (conv == 0) ? 1 : (conv == 1) ? 2 : (conv == 2) ? 3 : 7;
    const int lead  = (conv == 2) ? 1 : (conv == 3) ? 3 : 0;
    const int wbase = (conv == 0) ? 0 : (conv == 1) ? 122880 : (conv == 2) ? 368640 : 737280;

    const int b  = nt >> 2;
    const int l0 = (nt & 3) << 7;
    const short* xbs = (const short*)xbg + (b * XBP + l0) * XBC;   // row i <-> l = l0 + i - 3
    const short* wbp = (const short*)Wbg + wbase;

    floatx16 acc00, acc01, acc10, acc11;
    for (int i = 0; i < 16; i++) { acc00[i] = 0.f; acc01[i] = 0.f; acc10[i] = 0.f; acc11[i] = 0.f; }

    for (int chunk = 0; chunk < 10; chunk++) {
        const int c0 = chunk * 32;
        __syncthreads();
        for (int j = tid; j < 536; j += 256) {           // 134 rows x 4 vec8
            int row = j >> 2, cj = (j & 3) << 3;
            *(short8*)&xs[row * 40 + cj] = *(const short8*)&xbs[row * XBC + c0 + cj];
        }
        for (int t = 0; t < taps; t++) {
            if (t) __syncthreads();
            for (int j = tid; j < 512; j += 256) {       // 128 rows x 4 vec8
                int row = j >> 2, cj = (j & 3) << 3;
                *(short8*)&wl[row * 40 + cj] =
                    *(const short8*)&wbp[(m0 + row) * (taps * 320) + chunk * (taps * 32) + t * 32 + cj];
            }
            __syncthreads();
            const int arow = (wn * 64 + lr + t - lead + 3) * 40 + lk;
            const int brow = (wm * 64 + lr) * 40 + lk;
#pragma unroll
            for (int ks = 0; ks < 2; ks++) {
                short8 a0 = *(const short8*)&xs[arow + ks * 16];
                short8 a1 = *(const short8*)&xs[arow + 32 * 40 + ks * 16];
                short8 b0 = *(const short8*)&wl[brow + ks * 16];
                short8 b1 = *(const short8*)&wl[brow + 32 * 40 + ks * 16];
                acc00 = __builtin_amdgcn_mfma_f32_32x32x16_bf16(a0, b0, acc00, 0, 0, 0);
                acc01 = __builtin_amdgcn_mfma_f32_32x32x16_bf16(a0, b1, acc01, 0, 0, 0);
                acc10 = __builtin_amdgcn_mfma_f32_32x32x16_bf16(a1, b0, acc10, 0, 0, 0);
                acc11 = __builtin_amdgcn_mfma_f32_32x32x16_bf16(a1, b1, acc11, 0, 0, 0);
            }
        }
    }

    const float* bias = (conv == 0) ? bias1 : (conv == 1) ? bias2 : (conv == 2) ? bias3 : bias7;
#pragma unroll
    for (int msub = 0; msub < 2; msub++) {
        int mloc = m0 + wm * 64 + msub * 32 + lr;
        if (mloc < Cn) {
            float bv = bias[mloc];
            int col = conv * Cn + mloc;
#pragma unroll
            for (int nsub = 0; nsub < 2; nsub++) {
                floatx16 a = (msub == 0) ? (nsub == 0 ? acc00 : acc10)
                                         : (nsub == 0 ? acc01 : acc11);
#pragma unroll
                for (int reg = 0; reg < 16; reg++) {
                    int nl = wn * 64 + nsub * 32 + (reg & 3) + ((reg >> 2) << 3) + ((lane >> 5) << 2);
                    int n = nt * 128 + nl;
                    hbuf[n * HK + col] = __float2bfloat16(tanhf(a[reg] + bv));
                }
            }
        }
    }
}

// ---------------- linear GEMM ----------------
// grid (128 n-tiles, 4 h-tiles), block 256; same tile shape; K = 1216
__global__ __launch_bounds__(256) void linear_kernel(
        const __hip_bfloat16* __restrict__ hbufg, const __hip_bfloat16* __restrict__ Wcg,
        const float* __restrict__ slp_b, float* __restrict__ out) {
    __shared__ __align__(16) short hs[128 * 40];
    __shared__ __align__(16) short wl[128 * 40];

    const int tid  = threadIdx.x;
    const int lane = tid & 63;
    const int wave = tid >> 6;
    const int wn = wave & 1, wm = wave >> 1;
    const int lr = lane & 31;
    const int lk = (lane >> 5) * 8;

    const int nt = blockIdx.x;
    const int m0 = blockIdx.y * 128;

    const short* hb = (const short*)hbufg + nt * 128 * HK;
    const short* wc = (const short*)Wcg + m0 * HK;

    floatx16 acc00, acc01, acc10, acc11;
    for (int i = 0; i < 16; i++) { acc00[i] = 0.f; acc01[i] = 0.f; acc10[i] = 0.f; acc11[i] = 0.f; }

    for (int chunk = 0; chunk < 38; chunk++) {
        const int c0 = chunk * 32;
        __syncthreads();
        for (int j = tid; j < 512; j += 256) {
            int row = j >> 2, cj = (j & 3) << 3;
            *(short8*)&hs[row * 40 + cj] = *(const short8*)&hb[row * HK + c0 + cj];
            *(short8*)&wl[row * 40 + cj] = *(const short8*)&wc[row * HK + c0 + cj];
        }
        __syncthreads();
        const int arow = (wn * 64 + lr) * 40 + lk;
        const int brow = (wm * 64 + lr) * 40 + lk;
#pragma unroll
        for (int ks = 0; ks < 2; ks++) {
            short8 a0 = *(const short8*)&hs[arow + ks * 16];
            short8 a1 = *(const short8*)&hs[arow + 32 * 40 + ks * 16];
            short8 b0 = *(const short8*)&wl[brow + ks * 16];
            short8 b1 = *(const short8*)&wl[brow + 32 * 40 + ks * 16];
            acc00 = __builtin_amdgcn_mfma_f32_32x32x16_bf16(a0, b0, acc00, 0, 0, 0);
            acc01 = __builtin_amdgcn_mfma_f32_32x32x16_bf16(a0, b1, acc01, 0, 0, 0);
            acc10 = __builtin_amdgcn_mfma_f32_32x32x16_bf16(a1, b0, acc10, 0, 0, 0);
            acc11 = __builtin_amdgcn_mfma_f32_32x32x16_bf16(a1, b1, acc11, 0, 0, 0);
        }
    }

#pragma unroll
    for (int msub = 0; msub < 2; msub++) {
        int h = m0 + wm * 64 + msub * 32 + lr;
        float bv = slp_b[h];
#pragma unroll
        for (int nsub = 0; nsub < 2; nsub++) {
            floatx16 a = (msub == 0) ? (nsub == 0 ? acc00 : acc10)
                                     : (nsub == 0 ? acc01 : acc11);
#pragma unroll
            for (int reg = 0; reg < 16; reg++) {
                int nl = wn * 64 + nsub * 32 + (reg & 3) + ((reg >> 2) << 3) + ((lane >> 5) << 2);
                int n = nt * 128 + nl;
                out[n * Hn + h] = tanhf(a[reg] + bv);
            }
        }
    }
}

// ---------------- launch ----------------

extern "C" void kernel_launch(void* const* d_in, const int* in_sizes, int n_in,
                              void* d_out, int out_size, void* d_ws, size_t ws_size,
                              hipStream_t stream) {
    const float* x     = (const float*)d_in[0];
    const float* w1    = (const float*)d_in[1];
    const float* b1    = (const float*)d_in[2];
    const float* w2    = (const float*)d_in[3];
    const float* b2    = (const float*)d_in[4];
    const float* w3    = (const float*)d_in[5];
    const float* b3    = (const float*)d_in[6];
    const float* w7    = (const float*)d_in[7];
    const float* b7    = (const float*)d_in[8];
    const float* slp_w = (const float*)d_in[9];
    const float* slp_b = (const float*)d_in[10];

    __hip_bfloat16* wsb = (__hip_bfloat16*)d_ws;

    prep_x<<<(XB_ELEMS + 255) / 256, 256, 0, stream>>>(x, wsb + XB_OFF);
    prep_w<<<(WB_ELEMS + 255) / 256, 256, 0, stream>>>(w1, w2, w3, w7, wsb + WB_OFF);
    prep_wc<<<(WC_ELEMS + 255) / 256, 256, 0, stream>>>(slp_w, wsb + WC_OFF);

    conv_kernel<<<dim3(128, 12), 256, 0, stream>>>(wsb + XB_OFF, wsb + WB_OFF,
                                                   b1, b2, b3, b7, wsb + HB_OFF);
    linear_kernel<<<dim3(128, 4), 256, 0, stream>>>(wsb + HB_OFF, wsb + WC_OFF,
                                                    slp_b, (float*)d_out);
}